// Round 7
// baseline (6469.513 us; speedup 1.0000x reference)
//
#include <hip/hip_runtime.h>

// CosformerAttention: L=4096, B=4, E=1024, H=16, HD=64, n=B*H=64 heads.
// Round 7: inputs FLOAT32, output FLOAT32 (Story B — "reference's OUTPUT
// dtype" is f32; prior rounds wrongly stored bf16 into the f32 buffer).
// Full-scalar pipeline retained from round 6 for correctness isolation:
//  k_proj_s: scalar LDS-tiled f32 GEMM. Q (f32) -> d_out scratch, K,V (bf16) -> ws.
//  k_kv_s  : scalar kv[head][d][m] = sum_l feat_d(l)*relu_k(l,d&63)*v_ext(l,m)
//  k_attn_s: scalar out = (q_ . kv) / max(q_ . ksum, eps), f32 in/out of d_out.

typedef unsigned short ushortt;
typedef unsigned int u32;

#define L_DIM 4096
#define B_DIM 4
#define E_DIM 1024

__device__ __forceinline__ ushortt f2bf(float f) {
    union { float f; u32 u; } v; v.f = f;
    u32 u = v.u;
    u += 0x7FFFu + ((u >> 16) & 1u);   // round-to-nearest-even
    return (ushortt)(u >> 16);
}
__device__ __forceinline__ float bf2f(ushortt h) {
    union { u32 u; float f; } v; v.u = ((u32)h) << 16;
    return v.f;
}

// ---------------- Kernel 1 (scalar): projection GEMM --------------------------
// Y[m][n] = relu?(sum_k X[m][k] * W[n][k] + b[n]),  m = l*B+b (16384), n (1024).
// grid: x = 256 (M/64), y = 48 (proj*16 + ntile). block 256 = 16x16 threads,
// each thread computes a 4x4 output patch. Pure f32 scalar FMA from LDS.
// p==0 (Q): store f32 into Qf (= d_out). p==1,2 (K,V): store bf16 into ws.
__global__ __launch_bounds__(256) void k_proj_s(
    const float* __restrict__ xq, const float* __restrict__ xk, const float* __restrict__ xv,
    const float* __restrict__ wq, const float* __restrict__ bq,
    const float* __restrict__ wk, const float* __restrict__ bk,
    const float* __restrict__ wv, const float* __restrict__ bv,
    float* __restrict__ Qf, ushortt* __restrict__ Kb, ushortt* __restrict__ Vb)
{
    __shared__ float sX[64 * 33];   // 64 rows x 32 k, +1 pad
    __shared__ float sW[64 * 33];

    const int t = threadIdx.x;
    const int tx = t & 15, ty = t >> 4;

    const int p = blockIdx.y >> 4;             // 0=q, 1=k, 2=v
    const int nblk = (blockIdx.y & 15) * 64;   // output col base
    const int mblk = blockIdx.x * 64;          // output row base

    const float* X = (p == 0) ? xq : (p == 1) ? xk : xv;
    const float* W = (p == 0) ? wq : (p == 1) ? wk : wv;
    const float* bias = (p == 0) ? bq : (p == 1) ? bk : bv;
    const bool do_relu = (p < 2);

    float acc[4][4];
#pragma unroll
    for (int i = 0; i < 4; i++)
#pragma unroll
        for (int j = 0; j < 4; j++) acc[i][j] = 0.0f;

    for (int k0 = 0; k0 < 1024; k0 += 32) {
        __syncthreads();   // previous tile fully consumed
#pragma unroll
        for (int i = 0; i < 8; i++) {
            const int idx = t + 256 * i;       // 0..2047
            const int r = idx >> 5, c = idx & 31;
            sX[r * 33 + c] = X[(size_t)(mblk + r) * E_DIM + k0 + c];
            sW[r * 33 + c] = W[(size_t)(nblk + r) * E_DIM + k0 + c];
        }
        __syncthreads();
#pragma unroll 4
        for (int kk = 0; kk < 32; kk++) {
            float a[4], w[4];
#pragma unroll
            for (int i = 0; i < 4; i++) a[i] = sX[(ty * 4 + i) * 33 + kk];
#pragma unroll
            for (int j = 0; j < 4; j++) w[j] = sW[(tx * 4 + j) * 33 + kk];
#pragma unroll
            for (int i = 0; i < 4; i++)
#pragma unroll
                for (int j = 0; j < 4; j++) acc[i][j] += a[i] * w[j];
        }
    }

#pragma unroll
    for (int j = 0; j < 4; j++) {
        const int col = nblk + tx * 4 + j;
        const float bj = bias[col];
#pragma unroll
        for (int i = 0; i < 4; i++) {
            const int row = mblk + ty * 4 + i;
            float v = acc[i][j] + bj;
            if (do_relu) v = fmaxf(v, 0.0f);
            if (p == 0)      Qf[(size_t)row * E_DIM + col] = v;        // f32
            else if (p == 1) Kb[(size_t)row * E_DIM + col] = f2bf(v);  // bf16
            else             Vb[(size_t)row * E_DIM + col] = f2bf(v);  // bf16
        }
    }
}

// ---------------- Kernel 2 (scalar): kv[head][d][m], m in 0..64 --------------
// grid: x = 64 heads, y = 33 (ceil(128*65/256)). block 256. No LDS, no shfl.
__global__ __launch_bounds__(256) void k_kv_s(
    const ushortt* __restrict__ Kb, const ushortt* __restrict__ Vb,
    float* __restrict__ kv)
{
    const int head = blockIdx.x;
    const int idx = blockIdx.y * 256 + threadIdx.x;
    if (idx >= 128 * 65) return;
    const int d = idx / 65, m = idx % 65;
    const int b = head >> 4, hh = head & 15;
    const int dd = d & 63;
    const bool use_sin = (d < 64);

    float acc = 0.0f;
    for (int l = 0; l < L_DIM; ++l) {
        const float ang = 1.5707963267948966f * (float)(l + 1) * (1.0f / 4096.0f);
        const float f = use_sin ? sinf(ang) : cosf(ang);
        const size_t rowb = ((size_t)l * B_DIM + b) * E_DIM + hh * 64;
        const float kf = bf2f(Kb[rowb + dd]);           // relu'd k from k_proj_s
        const float vm = (m < 64) ? bf2f(Vb[rowb + m]) : 1.0f;
        acc += f * kf * vm;
    }
    kv[((size_t)head * 128 + d) * 65 + m] = acc;
}

// ---------------- Kernel 3 (scalar): out = (q_ . kv) / max(q_ . ksum, eps) ---
// grid: 65536 blocks x 256 threads = one thread per output element. f32 I/O.
// qout aliasing: block stages its OWN 256 q elements into LDS, barrier, then
// computes and overwrites exactly those elements. No cross-block sharing.
__global__ __launch_bounds__(256) void k_attn_s(
    float* qout, const float* __restrict__ kv)
{
    __shared__ float qs[256];
    const int t = threadIdx.x;
    const size_t idx = (size_t)blockIdx.x * 256 + t;
    const int l = (int)(idx >> 12);          // B*E = 4096
    const int rem = (int)(idx & 4095);
    const int b = rem >> 10;
    const int e = rem & 1023;
    const int hh = e >> 6;
    const int m = e & 63;
    const int head = b * 16 + hh;

    qs[t] = qout[idx];                       // relu'd q (f32) from k_proj_s
    __syncthreads();

    const float ang = 1.5707963267948966f * (float)(l + 1) * (1.0f / 4096.0f);
    const float s = sinf(ang), c = cosf(ang);
    const float* kvh = kv + (size_t)head * 128 * 65;
    const int qbase = t & 192;               // head-slice base within block

    float numer = 0.0f, den = 0.0f;
#pragma unroll 8
    for (int dd = 0; dd < 64; ++dd) {
        const float qv = qs[qbase + dd];
        numer += qv * (s * kvh[dd * 65 + m] + c * kvh[(dd + 64) * 65 + m]);
        den   += qv * (s * kvh[dd * 65 + 64] + c * kvh[(dd + 64) * 65 + 64]);
    }
    const float z = 1.0f / fmaxf(den, 1e-4f);
    qout[idx] = numer * z;                   // f32 output
}

extern "C" void kernel_launch(void* const* d_in, const int* in_sizes, int n_in,
                              void* d_out, int out_size, void* d_ws, size_t ws_size,
                              hipStream_t stream) {
    (void)in_sizes; (void)n_in; (void)out_size; (void)ws_size;
    const float* xq = (const float*)d_in[0];
    const float* xk = (const float*)d_in[1];
    const float* xv = (const float*)d_in[2];
    const float* wq = (const float*)d_in[3];
    const float* bq = (const float*)d_in[4];
    const float* wk = (const float*)d_in[5];
    const float* bk = (const float*)d_in[6];
    const float* wv = (const float*)d_in[7];
    const float* bv = (const float*)d_in[8];
    float* out = (float*)d_out;  // f32; doubles as Q-projection scratch

    char* ws = (char*)d_ws;
    // ws layout (bytes): Kb 33.55MB | Vb 33.55MB | kv 2.13MB => ~69.2MB
    ushortt* Kb = (ushortt*)(ws);
    ushortt* Vb = (ushortt*)(ws + 33554432);
    float* kv = (float*)(ws + 67108864);

    dim3 blk(256);
    k_proj_s<<<dim3(256, 48), blk, 0, stream>>>(xq, xk, xv, wq, bq, wk, bk, wv, bv, out, Kb, Vb);
    k_kv_s<<<dim3(64, 33), blk, 0, stream>>>(Kb, Vb, kv);
    k_attn_s<<<dim3(65536), blk, 0, stream>>>(out, kv);
}